// Round 12
// baseline (188.776 us; speedup 1.0000x reference)
//
#include <hip/hip_runtime.h>

typedef short bf16x8 __attribute__((ext_vector_type(8)));
typedef float f32x4 __attribute__((ext_vector_type(4)));

__device__ __forceinline__ unsigned short f2b(float f) {
    unsigned int u = __builtin_bit_cast(unsigned int, f);
    unsigned int r = u + 0x7FFFu + ((u >> 16) & 1u);
    return (unsigned short)(r >> 16);
}
__device__ __forceinline__ float wsum64(float v) {
    #pragma unroll
    for (int m = 32; m; m >>= 1) v += __shfl_xor(v, m, 64);
    return v;
}

// ---------------------------------------------------------------------------
// K_setup: all parallel prep. grid 2448 x 256.  (unchanged from R10)
__global__ __launch_bounds__(256) void k_setup(const float* __restrict__ w1,
                                               const float* __restrict__ wqkv,
                                               const float* __restrict__ b1,
                                               const float* __restrict__ bqkv,
                                               const float* __restrict__ gate_road_w,
                                               const float* __restrict__ ext_proj_w,
                                               const float* __restrict__ ext_qkv_w,
                                               const float* __restrict__ road_out_w,
                                               const float* __restrict__ low,
                                               unsigned short* __restrict__ W3b,
                                               unsigned short* __restrict__ Wcb,
                                               unsigned short* __restrict__ WF,
                                               float* __restrict__ bcv,
                                               float* __restrict__ mean_low) {
    int bid = blockIdx.x, t = threadIdx.x;
    __shared__ float sel[8][256];
    __shared__ float red[8][4];
    if (bid >= 400) {
        int bc = bid - 400;
        const f32x4* p4 = (const f32x4*)(low + (size_t)bc * 4096);
        float s = 0.f;
        for (int i = t; i < 1024; i += 256) {
            f32x4 v = p4[i];
            s += v[0] + v[1] + v[2] + v[3];
        }
        s = wsum64(s);
        if ((t & 63) == 0) red[0][t >> 6] = s;
        __syncthreads();
        if (t == 0) mean_low[bc] = (red[0][0] + red[0][1] + red[0][2] + red[0][3]) * (1.0f / 4096.0f);
    } else if (bid < 256) {
        int i = bid * 256 + t;
        int o = i >> 8, k = i & 255;
        W3b[i] = f2b(gate_road_w[o * 512 + k]);
    } else if (bid < 320) {
        int o0 = (bid - 256) * 8;
        #pragma unroll
        for (int r = 0; r < 8; r++) {
            int o = o0 + r;
            int c = (o < 256) ? o : o - 256;
            int g = (o < 256) ? 1 : 2;
            sel[r][t] = wqkv[(size_t)(3 * c + g) * 256 + t];
        }
        __syncthreads();
        float b1v = b1[t];
        #pragma unroll
        for (int r = 0; r < 8; r++) {
            float v = wsum64(sel[r][t] * b1v);
            if ((t & 63) == 0) red[r][t >> 6] = v;
        }
        __syncthreads();
        if (t < 8) {
            int o = o0 + t;
            int c = (o < 256) ? o : o - 256;
            int g = (o < 256) ? 1 : 2;
            bcv[o] = red[t][0] + red[t][1] + red[t][2] + red[t][3] + bqkv[3 * c + g];
        }
        float acc[8] = {};
        #pragma unroll 16
        for (int m = 0; m < 256; m++) {
            float w1v = w1[(size_t)m * 256 + t];
            #pragma unroll
            for (int r = 0; r < 8; r++) acc[r] += sel[r][m] * w1v;
        }
        #pragma unroll
        for (int r = 0; r < 8; r++) Wcb[(size_t)(o0 + r) * 256 + t] = f2b(acc[r]);
    } else {
        int mb = bid - 320;
        int m = mb >> 4, ctile = mb & 15;
        const float* src;
        int stride, K, coff;
        unsigned short* dst;
        if (m == 0)      { src = ext_qkv_w;                     stride = 256; K = 256; coff = 0;   dst = WF; }
        else if (m == 1) { src = ext_qkv_w + (size_t)512 * 256; stride = 256; K = 256; coff = 0;   dst = WF + 65536; }
        else if (m == 2) { src = road_out_w;                    stride = 256; K = 256; coff = 0;   dst = WF + 131072; }
        else if (m == 3) { src = gate_road_w;                   stride = 512; K = 256; coff = 256; dst = WF + 196608; }
        else             { src = ext_proj_w;                    stride = 64;  K = 64;  coff = 0;   dst = WF + 262144; }
        int lc = t >> 4, kseg = t & 15;
        int k0 = kseg * 16;
        if (k0 < K) {
            int c = ctile * 16 + lc;
            const float* sp = src + (size_t)c * stride + coff + k0;
            f32x4 v0 = *(const f32x4*)sp;
            f32x4 v1 = *(const f32x4*)(sp + 4);
            f32x4 v2 = *(const f32x4*)(sp + 8);
            f32x4 v3 = *(const f32x4*)(sp + 12);
            int kk = kseg >> 1;
            int Kt = K >> 5;
            #pragma unroll
            for (int h = 0; h < 2; h++) {
                int lhi = (kseg & 1) * 2 + h;
                int lane = lhi * 16 + lc;
                bf16x8 o;
                f32x4 a = h ? v2 : v0, b = h ? v3 : v1;
                #pragma unroll
                for (int i = 0; i < 4; i++) { o[i] = (short)f2b(a[i]); o[4 + i] = (short)f2b(b[i]); }
                *(bf16x8*)(dst + ((size_t)(ctile * Kt + kk) << 9) + lane * 8) = o;
            }
        }
    }
}

// ---------------------------------------------------------------------------
// K_tiny: 4-hop vector chain via MFMA, 1 block x 256. (unchanged from R10)
__global__ __launch_bounds__(256) void k_tiny(const unsigned short* __restrict__ WF,
                                              const float* __restrict__ ext_context,
                                              const float* __restrict__ ext_proj_b,
                                              const float* __restrict__ ext_qkv_b,
                                              const float* __restrict__ road_out_b,
                                              const float* __restrict__ gate_road_b,
                                              float* __restrict__ ext_q,
                                              float* __restrict__ road_vec,
                                              float* __restrict__ rg_const) {
    __shared__ unsigned short xA[16][264];
    __shared__ unsigned short xB[16][264];
    int t = threadIdx.x;
    int w = t >> 6, lane = t & 63, l15 = lane & 15, lhi = lane >> 4;
    const unsigned short* WqF  = WF;
    const unsigned short* WvF  = WF + 65536;
    const unsigned short* WroF = WF + 131072;
    const unsigned short* WgF  = WF + 196608;
    const unsigned short* WpF  = WF + 262144;
    for (int i = t; i < 8 * 132; i += 256) {
        int r = 8 + i / 132, cc = (i % 132) * 2;
        *(unsigned int*)&xA[r][cc] = 0;
        *(unsigned int*)&xB[r][cc] = 0;
    }
    {
        int b = t >> 5, k0 = (t & 31) * 2;
        float c0v = ext_context[b * 64 + k0];
        float c1v = ext_context[b * 64 + k0 + 1];
        *(unsigned int*)&xA[b][k0] = (unsigned int)f2b(c0v) | ((unsigned int)f2b(c1v) << 16);
    }
    __syncthreads();
    {
        f32x4 acc[4] = {};
        #pragma unroll
        for (int kk = 0; kk < 2; kk++) {
            bf16x8 a = *(const bf16x8*)&xA[l15][kk * 32 + 8 * lhi];
            #pragma unroll
            for (int ni = 0; ni < 4; ni++) {
                int ct = w * 4 + ni;
                bf16x8 bfr = *(const bf16x8*)(WpF + ((size_t)(ct * 2 + kk) << 9) + lane * 8);
                acc[ni] = __builtin_amdgcn_mfma_f32_16x16x32_bf16(a, bfr, acc[ni], 0, 0, 0);
            }
        }
        if (lhi < 2) {
            #pragma unroll
            for (int ni = 0; ni < 4; ni++) {
                int c = w * 64 + ni * 16 + l15;
                float bp = ext_proj_b[c];
                #pragma unroll
                for (int r = 0; r < 4; r++)
                    xB[4 * lhi + r][c] = f2b(acc[ni][r] + bp);
            }
        }
    }
    __syncthreads();
    {
        f32x4 acc[8] = {};
        bool isq = (w < 2);
        int cbase = (w & 1) * 128;
        const unsigned short* Wb = isq ? WqF : WvF;
        for (int kk = 0; kk < 8; kk++) {
            bf16x8 a = *(const bf16x8*)&xB[l15][kk * 32 + 8 * lhi];
            #pragma unroll
            for (int ni = 0; ni < 8; ni++) {
                int ct = (cbase >> 4) + ni;
                bf16x8 bfr = *(const bf16x8*)(Wb + ((size_t)(ct * 8 + kk) << 9) + lane * 8);
                acc[ni] = __builtin_amdgcn_mfma_f32_16x16x32_bf16(a, bfr, acc[ni], 0, 0, 0);
            }
        }
        if (lhi < 2) {
            #pragma unroll
            for (int ni = 0; ni < 8; ni++) {
                int c = cbase + ni * 16 + l15;
                float bb = ext_qkv_b[(isq ? 0 : 512) + c];
                #pragma unroll
                for (int r = 0; r < 4; r++) {
                    int b = 4 * lhi + r;
                    float val = acc[ni][r] + bb;
                    if (isq) ext_q[b * 256 + c] = val;
                    else     xA[b][c] = f2b(val);
                }
            }
        }
    }
    __syncthreads();
    {
        f32x4 acc[4] = {};
        for (int kk = 0; kk < 8; kk++) {
            bf16x8 a = *(const bf16x8*)&xA[l15][kk * 32 + 8 * lhi];
            #pragma unroll
            for (int ni = 0; ni < 4; ni++) {
                int ct = w * 4 + ni;
                bf16x8 bfr = *(const bf16x8*)(WroF + ((size_t)(ct * 8 + kk) << 9) + lane * 8);
                acc[ni] = __builtin_amdgcn_mfma_f32_16x16x32_bf16(a, bfr, acc[ni], 0, 0, 0);
            }
        }
        if (lhi < 2) {
            #pragma unroll
            for (int ni = 0; ni < 4; ni++) {
                int c = w * 64 + ni * 16 + l15;
                float bb = road_out_b[c];
                #pragma unroll
                for (int r = 0; r < 4; r++) {
                    int b = 4 * lhi + r;
                    float val = acc[ni][r] + bb;
                    road_vec[b * 256 + c] = val;
                    xB[b][c] = f2b(val);
                }
            }
        }
    }
    __syncthreads();
    {
        f32x4 acc[4] = {};
        for (int kk = 0; kk < 8; kk++) {
            bf16x8 a = *(const bf16x8*)&xB[l15][kk * 32 + 8 * lhi];
            #pragma unroll
            for (int ni = 0; ni < 4; ni++) {
                int ct = w * 4 + ni;
                bf16x8 bfr = *(const bf16x8*)(WgF + ((size_t)(ct * 8 + kk) << 9) + lane * 8);
                acc[ni] = __builtin_amdgcn_mfma_f32_16x16x32_bf16(a, bfr, acc[ni], 0, 0, 0);
            }
        }
        if (lhi < 2) {
            #pragma unroll
            for (int ni = 0; ni < 4; ni++) {
                int c = w * 64 + ni * 16 + l15;
                float bb = gate_road_b[c];
                #pragma unroll
                for (int r = 0; r < 4; r++)
                    rg_const[(4 * lhi + r) * 256 + c] = acc[ni][r] + bb;
            }
        }
    }
}

// ---------------------------------------------------------------------------
// K_kv: persistent 2-tile, double-buffered LDS, register-staged prefetch.
// grid 512, block 512 (8 waves). Block handles tiles {bid, bid+512}.
__global__ __launch_bounds__(512) void k_kv(const float* __restrict__ road_feat,
                                            const unsigned short* __restrict__ Wcb,
                                            const float* __restrict__ bcv,
                                            const float* __restrict__ extq,
                                            float* __restrict__ part) {
    __shared__ unsigned short Xs[2][32 * 256];   // 2 x 16 KB, swizzled bf16
    __shared__ float esh[2][8][32];
    int t = threadIdx.x;
    int w = t >> 6, lane = t & 63, l15 = lane & 15, lhi = lane >> 4;
    int c0 = 2 * (t >> 3);
    int j4 = (t & 7) * 4;
    f32x4 g0, g1, g2, g3;

    auto LOAD = [&](int tl) {
        const float* rfb = road_feat + (size_t)(tl >> 7) * 1048576 + ((tl & 127) << 5);
        g0 = *(const f32x4*)(rfb + (size_t)c0 * 4096 + j4);
        g1 = *(const f32x4*)(rfb + (size_t)(c0 + 1) * 4096 + j4);
        g2 = *(const f32x4*)(rfb + (size_t)(c0 + 128) * 4096 + j4);
        g3 = *(const f32x4*)(rfb + (size_t)(c0 + 129) * 4096 + j4);
    };
    auto WRITE = [&](int buf) {
        char* Xc = (char*)Xs[buf];
        #pragma unroll
        for (int i = 0; i < 4; i++) {
            int j = j4 + i;
            int sw = (j & 15) << 4;
            unsigned int pkA = (unsigned int)f2b(g0[i]) | ((unsigned int)f2b(g1[i]) << 16);
            unsigned int pkB = (unsigned int)f2b(g2[i]) | ((unsigned int)f2b(g3[i]) << 16);
            *(unsigned int*)(Xc + ((j * 512 + 2 * c0) ^ sw)) = pkA;
            *(unsigned int*)(Xc + ((j * 512 + 2 * (c0 + 128)) ^ sw)) = pkB;
        }
    };
    auto COMPUTE = [&](int buf, int tl) {
        char* Xc = (char*)Xs[buf];
        int b = tl >> 7;
        f32x4 acc[2][4] = {};
        for (int kk = 0; kk < 8; kk++) {
            int base = (kk * 32 + 8 * lhi) * 2;
            bf16x8 a0 = *(const bf16x8*)(Xc + ((l15 * 512 + base) ^ (l15 << 4)));
            bf16x8 a1 = *(const bf16x8*)(Xc + (((16 + l15) * 512 + base) ^ (l15 << 4)));
            #pragma unroll
            for (int ni = 0; ni < 4; ni++) {
                bf16x8 wfr = *(const bf16x8*)(Wcb + (size_t)(w * 64 + ni * 16 + l15) * 256 + kk * 32 + 8 * lhi);
                acc[0][ni] = __builtin_amdgcn_mfma_f32_16x16x32_bf16(a0, wfr, acc[0][ni], 0, 0, 0);
                acc[1][ni] = __builtin_amdgcn_mfma_f32_16x16x32_bf16(a1, wfr, acc[1][ni], 0, 0, 0);
            }
        }
        if (w < 4) {
            float qv[4], bk[4];
            #pragma unroll
            for (int ni = 0; ni < 4; ni++) {
                int n = w * 64 + ni * 16 + l15;
                qv[ni] = extq[b * 256 + n];
                bk[ni] = bcv[n];
            }
            #pragma unroll
            for (int mi = 0; mi < 2; mi++)
                #pragma unroll
                for (int r = 0; r < 4; r++) {
                    int j = mi * 16 + 4 * lhi + r;
                    #pragma unroll
                    for (int hl = 0; hl < 2; hl++) {
                        float s = (acc[mi][2 * hl][r] + bk[2 * hl]) * qv[2 * hl]
                                + (acc[mi][2 * hl + 1][r] + bk[2 * hl + 1]) * qv[2 * hl + 1];
                        s += __shfl_xor(s, 1, 64);
                        s += __shfl_xor(s, 2, 64);
                        s += __shfl_xor(s, 4, 64);
                        s += __shfl_xor(s, 8, 64);
                        if (l15 == 0)
                            esh[buf][w * 2 + hl][j] = expf(s * 0.17677669529663687f);
                    }
                }
        }
        __syncthreads();
        float* pb = part + (size_t)tl * 264;
        if (w >= 4) {
            #pragma unroll
            for (int ni = 0; ni < 4; ni++) {
                int cv = (w - 4) * 64 + ni * 16 + l15;
                int hg = (w - 4) * 2 + (ni >> 1);
                float bv = bcv[256 + cv];
                float p = 0.f;
                #pragma unroll
                for (int mi = 0; mi < 2; mi++)
                    #pragma unroll
                    for (int r = 0; r < 4; r++) {
                        int j = mi * 16 + 4 * lhi + r;
                        p += esh[buf][hg][j] * (acc[mi][ni][r] + bv);
                    }
                p += __shfl_xor(p, 16, 64);
                p += __shfl_xor(p, 32, 64);
                if (lhi == 0) pb[8 + cv] = p;
            }
        } else {
            int h0 = w * 2;
            float v0 = (lane < 32) ? esh[buf][h0][lane] : esh[buf][h0 + 1][lane - 32];
            v0 += __shfl_xor(v0, 1, 64);
            v0 += __shfl_xor(v0, 2, 64);
            v0 += __shfl_xor(v0, 4, 64);
            v0 += __shfl_xor(v0, 8, 64);
            v0 += __shfl_xor(v0, 16, 64);
            if (lane == 0)  pb[h0] = v0;
            if (lane == 32) pb[h0 + 1] = v0;
        }
    };

    int t0 = blockIdx.x, t1 = blockIdx.x + 512;
    LOAD(t0);
    WRITE(0);
    __syncthreads();
    LOAD(t1);                 // in flight across tile0 compute
    COMPUTE(0, t0);
    WRITE(1);                 // vmcnt drain happens here, after compute0
    __syncthreads();
    COMPUTE(1, t1);
}

// ---------------------------------------------------------------------------
// K_road: persistent 2-tile, double-buffered. grid 512, block 512.
__global__ __launch_bounds__(512) void k_road(const float* __restrict__ high,
                                              const unsigned short* __restrict__ W3b,
                                              const float* __restrict__ rg_const,
                                              const float* __restrict__ road_vec,
                                              float* __restrict__ outbuf) {
    __shared__ float Xs[2][32 * 256];   // 2 x 32 KB f32, swizzled
    int t = threadIdx.x;
    int w = t >> 6, lane = t & 63, l15 = lane & 15, lhi = lane >> 4;
    int c0 = t >> 3;
    int j4 = (t & 7) * 4;
    f32x4 g0, g1, g2, g3;

    auto LOAD = [&](int tl) {
        const float* hb = high + (size_t)(tl >> 7) * 1048576 + ((tl & 127) << 5);
        g0 = *(const f32x4*)(hb + (size_t)c0 * 4096 + j4);
        g1 = *(const f32x4*)(hb + (size_t)(c0 + 64) * 4096 + j4);
        g2 = *(const f32x4*)(hb + (size_t)(c0 + 128) * 4096 + j4);
        g3 = *(const f32x4*)(hb + (size_t)(c0 + 192) * 4096 + j4);
    };
    auto WRITE = [&](int buf) {
        char* Xc = (char*)Xs[buf];
        #pragma unroll
        for (int i = 0; i < 4; i++) {
            int j = j4 + i;
            int sw = (j & 15) << 4;
            *(float*)(Xc + ((j * 1024 + 4 * c0) ^ sw))         = g0[i];
            *(float*)(Xc + ((j * 1024 + 4 * (c0 + 64)) ^ sw))  = g1[i];
            *(float*)(Xc + ((j * 1024 + 4 * (c0 + 128)) ^ sw)) = g2[i];
            *(float*)(Xc + ((j * 1024 + 4 * (c0 + 192)) ^ sw)) = g3[i];
        }
    };

    int tl0 = blockIdx.x, tl1 = blockIdx.x + 512;
    f32x4 acc[2][2];

    auto GEMM = [&](int buf) {
        char* Xc = (char*)Xs[buf];
        acc[0][0] = f32x4{}; acc[0][1] = f32x4{};
        acc[1][0] = f32x4{}; acc[1][1] = f32x4{};
        for (int kk = 0; kk < 8; kk++) {
            int base = (kk * 32 + 8 * lhi) * 4;
            int sw0 = l15 << 4;
            f32x4 x0 = *(const f32x4*)(Xc + ((l15 * 1024 + base) ^ sw0));
            f32x4 x1 = *(const f32x4*)(Xc + ((l15 * 1024 + base + 16) ^ sw0));
            f32x4 y0 = *(const f32x4*)(Xc + (((16 + l15) * 1024 + base) ^ sw0));
            f32x4 y1 = *(const f32x4*)(Xc + (((16 + l15) * 1024 + base + 16) ^ sw0));
            bf16x8 a0, a1;
            #pragma unroll
            for (int i = 0; i < 4; i++) {
                a0[i] = (short)f2b(x0[i]); a0[4 + i] = (short)f2b(x1[i]);
                a1[i] = (short)f2b(y0[i]); a1[4 + i] = (short)f2b(y1[i]);
            }
            #pragma unroll
            for (int ni = 0; ni < 2; ni++) {
                bf16x8 wfr = *(const bf16x8*)(W3b + (size_t)(w * 32 + ni * 16 + l15) * 256 + kk * 32 + 8 * lhi);
                acc[0][ni] = __builtin_amdgcn_mfma_f32_16x16x32_bf16(a0, wfr, acc[0][ni], 0, 0, 0);
                acc[1][ni] = __builtin_amdgcn_mfma_f32_16x16x32_bf16(a1, wfr, acc[1][ni], 0, 0, 0);
            }
        }
    };
    auto GATE = [&](int buf, int b) {
        char* Xc = (char*)Xs[buf];
        #pragma unroll
        for (int ni = 0; ni < 2; ni++) {
            int o = w * 32 + ni * 16 + l15;
            float rc = rg_const[b * 256 + o];
            float rv = road_vec[b * 256 + o];
            #pragma unroll
            for (int mi = 0; mi < 2; mi++)
                #pragma unroll
                for (int r = 0; r < 4; r++) {
                    int j = mi * 16 + 4 * lhi + r;
                    float* slot = (float*)(Xc + ((j * 1024 + 4 * o) ^ ((j & 15) << 4)));
                    float z = acc[mi][ni][r] + rc;
                    float gte = 1.0f / (1.0f + expf(-z));
                    float hv = *slot;
                    *slot = hv + gte * (rv - hv);
                }
        }
    };
    auto STREAMOUT = [&](int buf, int tl) {
        char* Xc = (char*)Xs[buf];
        float* ob = outbuf + 8388608 + (size_t)(tl >> 7) * 1048576 + ((tl & 127) << 5);
        #pragma unroll
        for (int it = 0; it < 4; ++it) {
            int c = c0 + 64 * it;
            f32x4 o4;
            #pragma unroll
            for (int i = 0; i < 4; i++) {
                int j = j4 + i;
                o4[i] = *(const float*)(Xc + ((j * 1024 + 4 * c) ^ ((j & 15) << 4)));
            }
            *(f32x4*)(ob + (size_t)c * 4096 + j4) = o4;
        }
    };

    LOAD(tl0);
    WRITE(0);
    __syncthreads();
    LOAD(tl1);                 // hidden under tile0 GEMM
    GEMM(0);
    __syncthreads();           // all K-loop reads of buf0 done
    WRITE(1);                  // vmcnt drain here
    GATE(0, tl0 >> 7);         // in-place on buf0 (owner-lane exclusive)
    __syncthreads();           // buf0 gated + buf1 staged
    STREAMOUT(0, tl0);
    GEMM(1);
    __syncthreads();
    GATE(1, tl1 >> 7);
    __syncthreads();
    STREAMOUT(1, tl1);
}

// ---------------------------------------------------------------------------
// K4: combine attention partials -> ext_head, then ext_vec / ext_gate. 8 blocks.
__global__ __launch_bounds__(256) void k_vec(const float* __restrict__ part,
                                             const float* __restrict__ ext_out_w,
                                             const float* __restrict__ ext_out_b,
                                             const float* __restrict__ mean_low,
                                             const float* __restrict__ gate_ext_w,
                                             const float* __restrict__ gate_ext_b,
                                             float* __restrict__ ext_vec,
                                             float* __restrict__ ext_gate) {
    int b = blockIdx.x, c = threadIdx.x;
    __shared__ float hd_[256], ev[256], ml[256], tot[8];
    const float* pb = part + (size_t)b * 128 * 264;
    float a = 0.f;
    #pragma unroll 4
    for (int tile = 0; tile < 128; tile++) a += pb[tile * 264 + 8 + c];
    if (c < 8) {
        float s = 0.f;
        for (int tile = 0; tile < 128; tile++) s += pb[tile * 264 + c];
        tot[c] = 1.0f / s;
    }
    ml[c] = mean_low[b * 256 + c];
    __syncthreads();
    hd_[c] = a * tot[c >> 5];
    __syncthreads();
    float s = ext_out_b[c];
    #pragma unroll 4
    for (int k = 0; k < 256; k++) s += ext_out_w[c * 256 + k] * hd_[k];
    ext_vec[b * 256 + c] = s;
    ev[c] = s;
    __syncthreads();
    float z = gate_ext_b[c];
    #pragma unroll 4
    for (int k = 0; k < 256; k++)
        z += gate_ext_w[c * 512 + k] * ml[k] + gate_ext_w[c * 512 + 256 + k] * ev[k];
    ext_gate[b * 256 + c] = 1.0f / (1.0f + expf(-z));
}

// ---------------------------------------------------------------------------
// K5: ext_final
__global__ __launch_bounds__(256) void k_ext_final(const float* __restrict__ low,
                                                   const float* __restrict__ ext_vec,
                                                   const float* __restrict__ ext_gate,
                                                   float* __restrict__ out) {
    int idx = blockIdx.x * 256 + threadIdx.x;
    #pragma unroll
    for (int rep = 0; rep < 4; ++rep) {
        int i = idx + rep * 524288;
        int bc = i >> 10;
        float g = ext_gate[bc];
        float vv = ext_vec[bc];
        f32x4 L = *(const f32x4*)(low + (size_t)i * 4);
        f32x4 o;
        #pragma unroll
        for (int c = 0; c < 4; c++) o[c] = L[c] + g * (vv - L[c]);
        *(f32x4*)(out + (size_t)i * 4) = o;
    }
}

// ---------------------------------------------------------------------------
extern "C" void kernel_launch(void* const* d_in, const int* in_sizes, int n_in,
                              void* d_out, int out_size, void* d_ws, size_t ws_size,
                              hipStream_t stream) {
    const float* low         = (const float*)d_in[0];
    const float* high        = (const float*)d_in[1];
    const float* ext_context = (const float*)d_in[2];
    const float* road_feat   = (const float*)d_in[3];
    const float* ext_proj_w  = (const float*)d_in[4];
    const float* ext_proj_b  = (const float*)d_in[5];
    const float* road_proj_w = (const float*)d_in[6];
    const float* road_proj_b = (const float*)d_in[7];
    const float* ext_qkv_w   = (const float*)d_in[8];
    const float* ext_qkv_b   = (const float*)d_in[9];
    const float* road_qkv_w  = (const float*)d_in[10];
    const float* road_qkv_b  = (const float*)d_in[11];
    const float* ext_out_w   = (const float*)d_in[12];
    const float* ext_out_b   = (const float*)d_in[13];
    const float* road_out_w  = (const float*)d_in[14];
    const float* road_out_b  = (const float*)d_in[15];
    const float* gate_ext_w  = (const float*)d_in[16];
    const float* gate_ext_b  = (const float*)d_in[17];
    const float* gate_road_w = (const float*)d_in[18];
    const float* gate_road_b = (const float*)d_in[19];

    float* out = (float*)d_out;
    unsigned short* wsb = (unsigned short*)d_ws;
    unsigned short* Wcb = wsb;               // [0, 131072)
    unsigned short* W3b = wsb + 131072;      // [131072, 196608)
    unsigned short* WF  = wsb + 196608;      // fragments: 278528 ushorts
    float* fw = (float*)((char*)d_ws + 983040);
    float* ext_q    = fw;
    float* road_vec = fw + 2048;
    float* rg_const = fw + 4096;
    float* ext_vec  = fw + 8192;
    float* ext_gate = fw + 10240;
    float* mean_low = fw + 12288;
    float* bcv      = fw + 14336;
    float* part = out + 2097152;   // 1024*264 floats in ext-half dead zone (pre-K5)

    k_setup<<<2448, 256, 0, stream>>>(road_proj_w, road_qkv_w, road_proj_b, road_qkv_b,
                                      gate_road_w, ext_proj_w, ext_qkv_w, road_out_w, low,
                                      W3b, Wcb, WF, bcv, mean_low);
    k_tiny<<<1, 256, 0, stream>>>(WF, ext_context, ext_proj_b, ext_qkv_b,
                                  road_out_b, gate_road_b, ext_q, road_vec, rg_const);
    k_kv<<<512, 512, 0, stream>>>(road_feat, Wcb, bcv, ext_q, part);
    k_road<<<512, 512, 0, stream>>>(high, W3b, rg_const, road_vec, out);
    k_vec<<<8, 256, 0, stream>>>(part, ext_out_w, ext_out_b, mean_low,
                                 gate_ext_w, gate_ext_b, ext_vec, ext_gate);
    k_ext_final<<<2048, 256, 0, stream>>>(low, ext_vec, ext_gate, out);
}

// Round 13
// 156.092 us; speedup vs baseline: 1.2094x; 1.2094x over previous
//
#include <hip/hip_runtime.h>

typedef short bf16x8 __attribute__((ext_vector_type(8)));
typedef float f32x4 __attribute__((ext_vector_type(4)));

__device__ __forceinline__ unsigned short f2b(float f) {
    unsigned int u = __builtin_bit_cast(unsigned int, f);
    unsigned int r = u + 0x7FFFu + ((u >> 16) & 1u);
    return (unsigned short)(r >> 16);
}
__device__ __forceinline__ float wsum64(float v) {
    #pragma unroll
    for (int m = 32; m; m >>= 1) v += __shfl_xor(v, m, 64);
    return v;
}

// WF fragment offsets (ushorts): Wq 0, Wv 65536, Wro 131072, Wg2 196608,
// Wp 262144, Wo 278528, WgeLo 344064, WgeHi 409600. total 475136.

// ---------------------------------------------------------------------------
// K_setup: all parallel prep. grid 2496 x 256.
//   bid 0..255   : W3b = bf16(gate_road_w[:, :256])
//   256..319     : Wc fold (road_proj into road_qkv k/v rows) + bc
//   320..447     : chain+vec weights -> bf16 fragment-major (8 mats x 16 ctiles)
//   448..2495    : mean_low over spatial per (b,c)
__global__ __launch_bounds__(256) void k_setup(const float* __restrict__ w1,
                                               const float* __restrict__ wqkv,
                                               const float* __restrict__ b1,
                                               const float* __restrict__ bqkv,
                                               const float* __restrict__ gate_road_w,
                                               const float* __restrict__ ext_proj_w,
                                               const float* __restrict__ ext_qkv_w,
                                               const float* __restrict__ road_out_w,
                                               const float* __restrict__ ext_out_w,
                                               const float* __restrict__ gate_ext_w,
                                               const float* __restrict__ low,
                                               unsigned short* __restrict__ W3b,
                                               unsigned short* __restrict__ Wcb,
                                               unsigned short* __restrict__ WF,
                                               float* __restrict__ bcv,
                                               float* __restrict__ mean_low) {
    int bid = blockIdx.x, t = threadIdx.x;
    __shared__ float sel[8][256];
    __shared__ float red[8][4];
    if (bid >= 448) {
        int bc = bid - 448;
        const f32x4* p4 = (const f32x4*)(low + (size_t)bc * 4096);
        float s = 0.f;
        for (int i = t; i < 1024; i += 256) {
            f32x4 v = p4[i];
            s += v[0] + v[1] + v[2] + v[3];
        }
        s = wsum64(s);
        if ((t & 63) == 0) red[0][t >> 6] = s;
        __syncthreads();
        if (t == 0) mean_low[bc] = (red[0][0] + red[0][1] + red[0][2] + red[0][3]) * (1.0f / 4096.0f);
    } else if (bid < 256) {
        int i = bid * 256 + t;
        int o = i >> 8, k = i & 255;
        W3b[i] = f2b(gate_road_w[o * 512 + k]);
    } else if (bid < 320) {
        int o0 = (bid - 256) * 8;
        #pragma unroll
        for (int r = 0; r < 8; r++) {
            int o = o0 + r;
            int c = (o < 256) ? o : o - 256;
            int g = (o < 256) ? 1 : 2;
            sel[r][t] = wqkv[(size_t)(3 * c + g) * 256 + t];
        }
        __syncthreads();
        float b1v = b1[t];
        #pragma unroll
        for (int r = 0; r < 8; r++) {
            float v = wsum64(sel[r][t] * b1v);
            if ((t & 63) == 0) red[r][t >> 6] = v;
        }
        __syncthreads();
        if (t < 8) {
            int o = o0 + t;
            int c = (o < 256) ? o : o - 256;
            int g = (o < 256) ? 1 : 2;
            bcv[o] = red[t][0] + red[t][1] + red[t][2] + red[t][3] + bqkv[3 * c + g];
        }
        float acc[8] = {};
        #pragma unroll 16
        for (int m = 0; m < 256; m++) {
            float w1v = w1[(size_t)m * 256 + t];
            #pragma unroll
            for (int r = 0; r < 8; r++) acc[r] += sel[r][m] * w1v;
        }
        #pragma unroll
        for (int r = 0; r < 8; r++) Wcb[(size_t)(o0 + r) * 256 + t] = f2b(acc[r]);
    } else {
        // fragment-major bf16 conversion
        int mb = bid - 320;
        int m = mb >> 4, ctile = mb & 15;
        const float* src;
        int stride, K, coff;
        unsigned short* dst;
        switch (m) {
        case 0: src = ext_qkv_w;                     stride = 256; K = 256; coff = 0;   dst = WF;          break;
        case 1: src = ext_qkv_w + (size_t)512 * 256; stride = 256; K = 256; coff = 0;   dst = WF + 65536;  break;
        case 2: src = road_out_w;                    stride = 256; K = 256; coff = 0;   dst = WF + 131072; break;
        case 3: src = gate_road_w;                   stride = 512; K = 256; coff = 256; dst = WF + 196608; break;
        case 4: src = ext_proj_w;                    stride = 64;  K = 64;  coff = 0;   dst = WF + 262144; break;
        case 5: src = ext_out_w;                     stride = 256; K = 256; coff = 0;   dst = WF + 278528; break;
        case 6: src = gate_ext_w;                    stride = 512; K = 256; coff = 0;   dst = WF + 344064; break;
        default: src = gate_ext_w;                   stride = 512; K = 256; coff = 256; dst = WF + 409600; break;
        }
        int lc = t >> 4, kseg = t & 15;
        int k0 = kseg * 16;
        if (k0 < K) {
            int c = ctile * 16 + lc;
            const float* sp = src + (size_t)c * stride + coff + k0;
            f32x4 v0 = *(const f32x4*)sp;
            f32x4 v1 = *(const f32x4*)(sp + 4);
            f32x4 v2 = *(const f32x4*)(sp + 8);
            f32x4 v3 = *(const f32x4*)(sp + 12);
            int kk = kseg >> 1;
            int Kt = K >> 5;
            #pragma unroll
            for (int h = 0; h < 2; h++) {
                int lhi = (kseg & 1) * 2 + h;
                int lane = lhi * 16 + lc;
                bf16x8 o;
                f32x4 a = h ? v2 : v0, b = h ? v3 : v1;
                #pragma unroll
                for (int i = 0; i < 4; i++) { o[i] = (short)f2b(a[i]); o[4 + i] = (short)f2b(b[i]); }
                *(bf16x8*)(dst + ((size_t)(ctile * Kt + kk) << 9) + lane * 8) = o;
            }
        }
    }
}

// ---------------------------------------------------------------------------
// K_tiny: 4-hop vector chain via MFMA, 1 block x 256.
__global__ __launch_bounds__(256) void k_tiny(const unsigned short* __restrict__ WF,
                                              const float* __restrict__ ext_context,
                                              const float* __restrict__ ext_proj_b,
                                              const float* __restrict__ ext_qkv_b,
                                              const float* __restrict__ road_out_b,
                                              const float* __restrict__ gate_road_b,
                                              float* __restrict__ ext_q,
                                              float* __restrict__ road_vec,
                                              float* __restrict__ rg_const) {
    __shared__ unsigned short xA[16][264];
    __shared__ unsigned short xB[16][264];
    int t = threadIdx.x;
    int w = t >> 6, lane = t & 63, l15 = lane & 15, lhi = lane >> 4;
    const unsigned short* WqF  = WF;
    const unsigned short* WvF  = WF + 65536;
    const unsigned short* WroF = WF + 131072;
    const unsigned short* WgF  = WF + 196608;
    const unsigned short* WpF  = WF + 262144;
    {
        int b = t >> 5, k0 = (t & 31) * 2;
        float c0v = ext_context[b * 64 + k0];
        float c1v = ext_context[b * 64 + k0 + 1];
        *(unsigned int*)&xA[b][k0] = (unsigned int)f2b(c0v) | ((unsigned int)f2b(c1v) << 16);
    }
    __syncthreads();
    {
        f32x4 acc[4] = {};
        #pragma unroll
        for (int kk = 0; kk < 2; kk++) {
            bf16x8 a = *(const bf16x8*)&xA[l15][kk * 32 + 8 * lhi];
            #pragma unroll
            for (int ni = 0; ni < 4; ni++) {
                int ct = w * 4 + ni;
                bf16x8 bfr = *(const bf16x8*)(WpF + ((size_t)(ct * 2 + kk) << 9) + lane * 8);
                acc[ni] = __builtin_amdgcn_mfma_f32_16x16x32_bf16(a, bfr, acc[ni], 0, 0, 0);
            }
        }
        if (lhi < 2) {
            #pragma unroll
            for (int ni = 0; ni < 4; ni++) {
                int c = w * 64 + ni * 16 + l15;
                float bp = ext_proj_b[c];
                #pragma unroll
                for (int r = 0; r < 4; r++)
                    xB[4 * lhi + r][c] = f2b(acc[ni][r] + bp);
            }
        }
    }
    __syncthreads();
    {
        f32x4 acc[8] = {};
        bool isq = (w < 2);
        int cbase = (w & 1) * 128;
        const unsigned short* Wb = isq ? WqF : WvF;
        for (int kk = 0; kk < 8; kk++) {
            bf16x8 a = *(const bf16x8*)&xB[l15][kk * 32 + 8 * lhi];
            #pragma unroll
            for (int ni = 0; ni < 8; ni++) {
                int ct = (cbase >> 4) + ni;
                bf16x8 bfr = *(const bf16x8*)(Wb + ((size_t)(ct * 8 + kk) << 9) + lane * 8);
                acc[ni] = __builtin_amdgcn_mfma_f32_16x16x32_bf16(a, bfr, acc[ni], 0, 0, 0);
            }
        }
        if (lhi < 2) {
            #pragma unroll
            for (int ni = 0; ni < 8; ni++) {
                int c = cbase + ni * 16 + l15;
                float bb = ext_qkv_b[(isq ? 0 : 512) + c];
                #pragma unroll
                for (int r = 0; r < 4; r++) {
                    int b = 4 * lhi + r;
                    float val = acc[ni][r] + bb;
                    if (isq) ext_q[b * 256 + c] = val;
                    else     xA[b][c] = f2b(val);
                }
            }
        }
    }
    __syncthreads();
    {
        f32x4 acc[4] = {};
        for (int kk = 0; kk < 8; kk++) {
            bf16x8 a = *(const bf16x8*)&xA[l15][kk * 32 + 8 * lhi];
            #pragma unroll
            for (int ni = 0; ni < 4; ni++) {
                int ct = w * 4 + ni;
                bf16x8 bfr = *(const bf16x8*)(WroF + ((size_t)(ct * 8 + kk) << 9) + lane * 8);
                acc[ni] = __builtin_amdgcn_mfma_f32_16x16x32_bf16(a, bfr, acc[ni], 0, 0, 0);
            }
        }
        if (lhi < 2) {
            #pragma unroll
            for (int ni = 0; ni < 4; ni++) {
                int c = w * 64 + ni * 16 + l15;
                float bb = road_out_b[c];
                #pragma unroll
                for (int r = 0; r < 4; r++) {
                    int b = 4 * lhi + r;
                    float val = acc[ni][r] + bb;
                    road_vec[b * 256 + c] = val;
                    xB[b][c] = f2b(val);
                }
            }
        }
    }
    __syncthreads();
    {
        f32x4 acc[4] = {};
        for (int kk = 0; kk < 8; kk++) {
            bf16x8 a = *(const bf16x8*)&xB[l15][kk * 32 + 8 * lhi];
            #pragma unroll
            for (int ni = 0; ni < 4; ni++) {
                int ct = w * 4 + ni;
                bf16x8 bfr = *(const bf16x8*)(WgF + ((size_t)(ct * 8 + kk) << 9) + lane * 8);
                acc[ni] = __builtin_amdgcn_mfma_f32_16x16x32_bf16(a, bfr, acc[ni], 0, 0, 0);
            }
        }
        if (lhi < 2) {
            #pragma unroll
            for (int ni = 0; ni < 4; ni++) {
                int c = w * 64 + ni * 16 + l15;
                float bb = gate_road_b[c];
                #pragma unroll
                for (int r = 0; r < 4; r++)
                    rg_const[(4 * lhi + r) * 256 + c] = acc[ni][r] + bb;
            }
        }
    }
}

// ---------------------------------------------------------------------------
// K_kv: fused KV-GEMM + tile-local attention partials. 32-px tiles,
// grid 1024, XCD-swizzled so each XCD's road_feat slab fits its L2.
__global__ __launch_bounds__(512) void k_kv(const float* __restrict__ road_feat,
                                            const unsigned short* __restrict__ Wcb,
                                            const float* __restrict__ bcv,
                                            const float* __restrict__ extq,
                                            float* __restrict__ part) {
    __shared__ unsigned short Xs[32 * 256];
    __shared__ float esh[8][32];
    char* Xc = (char*)Xs;
    int bid = ((blockIdx.x & 7) << 7) | (blockIdx.x >> 3);   // XCD swizzle (1024%8==0)
    int b  = bid >> 7;
    int p0 = (bid & 127) << 5;
    int t  = threadIdx.x;
    const float* rfb = road_feat + (size_t)b * 1048576;

    int c0 = 2 * (t >> 3);
    int j4 = (t & 7) * 4;
    #pragma unroll
    for (int it = 0; it < 2; ++it) {
        int c = c0 + 128 * it;
        f32x4 g0 = *(const f32x4*)(rfb + (size_t)c * 4096 + p0 + j4);
        f32x4 g1 = *(const f32x4*)(rfb + (size_t)(c + 1) * 4096 + p0 + j4);
        #pragma unroll
        for (int i = 0; i < 4; i++) {
            int j = j4 + i;
            unsigned int pk = (unsigned int)f2b(g0[i]) | ((unsigned int)f2b(g1[i]) << 16);
            *(unsigned int*)(Xc + ((j * 512 + 2 * c) ^ ((j & 15) << 4))) = pk;
        }
    }
    __syncthreads();

    int w = t >> 6, lane = t & 63, l15 = lane & 15, lhi = lane >> 4;

    f32x4 acc[2][4] = {};
    for (int kk = 0; kk < 8; kk++) {
        bf16x8 a[2];
        #pragma unroll
        for (int mi = 0; mi < 2; mi++) {
            int j = mi * 16 + l15;
            int off = (j * 512 + (kk * 32 + 8 * lhi) * 2) ^ ((j & 15) << 4);
            a[mi] = *(const bf16x8*)((const char*)Xs + off);
        }
        #pragma unroll
        for (int ni = 0; ni < 4; ni++) {
            int n = w * 64 + ni * 16 + l15;
            bf16x8 bf = *(const bf16x8*)(Wcb + (size_t)n * 256 + kk * 32 + 8 * lhi);
            acc[0][ni] = __builtin_amdgcn_mfma_f32_16x16x32_bf16(a[0], bf, acc[0][ni], 0, 0, 0);
            acc[1][ni] = __builtin_amdgcn_mfma_f32_16x16x32_bf16(a[1], bf, acc[1][ni], 0, 0, 0);
        }
    }

    if (w < 4) {
        float qv[4], bk[4];
        #pragma unroll
        for (int ni = 0; ni < 4; ni++) {
            int n = w * 64 + ni * 16 + l15;
            qv[ni] = extq[b * 256 + n];
            bk[ni] = bcv[n];
        }
        #pragma unroll
        for (int mi = 0; mi < 2; mi++)
            #pragma unroll
            for (int r = 0; r < 4; r++) {
                int j = mi * 16 + 4 * lhi + r;
                #pragma unroll
                for (int hl = 0; hl < 2; hl++) {
                    float s = (acc[mi][2 * hl][r] + bk[2 * hl]) * qv[2 * hl]
                            + (acc[mi][2 * hl + 1][r] + bk[2 * hl + 1]) * qv[2 * hl + 1];
                    s += __shfl_xor(s, 1, 64);
                    s += __shfl_xor(s, 2, 64);
                    s += __shfl_xor(s, 4, 64);
                    s += __shfl_xor(s, 8, 64);
                    if (l15 == 0)
                        esh[w * 2 + hl][j] = expf(s * 0.17677669529663687f);
                }
            }
    }
    __syncthreads();

    float* pb = part + (size_t)bid * 264;
    if (w >= 4) {
        #pragma unroll
        for (int ni = 0; ni < 4; ni++) {
            int cv = (w - 4) * 64 + ni * 16 + l15;
            int hg = (w - 4) * 2 + (ni >> 1);
            float bv = bcv[256 + cv];
            float p = 0.f;
            #pragma unroll
            for (int mi = 0; mi < 2; mi++)
                #pragma unroll
                for (int r = 0; r < 4; r++) {
                    int j = mi * 16 + 4 * lhi + r;
                    p += esh[hg][j] * (acc[mi][ni][r] + bv);
                }
            p += __shfl_xor(p, 16, 64);
            p += __shfl_xor(p, 32, 64);
            if (lhi == 0) pb[8 + cv] = p;
        }
    } else {
        int h0 = w * 2;
        float v0 = (lane < 32) ? esh[h0][lane] : esh[h0 + 1][lane - 32];
        v0 += __shfl_xor(v0, 1, 64);
        v0 += __shfl_xor(v0, 2, 64);
        v0 += __shfl_xor(v0, 4, 64);
        v0 += __shfl_xor(v0, 8, 64);
        v0 += __shfl_xor(v0, 16, 64);
        if (lane == 0)  pb[h0] = v0;
        if (lane == 32) pb[h0 + 1] = v0;
    }
}

// ---------------------------------------------------------------------------
// K_vec_combine: 8 blocks x 256. Coalesced reduction of attention partials.
__global__ __launch_bounds__(256) void k_vec_combine(const float* __restrict__ part,
                                                     float* __restrict__ hdg) {
    int b = blockIdx.x, c = threadIdx.x;
    __shared__ float tot[8];
    const float* pb = part + (size_t)b * 128 * 264;
    float a = 0.f;
    #pragma unroll 8
    for (int tile = 0; tile < 128; tile++) a += pb[tile * 264 + 8 + c];
    if (c < 8) {
        float s = 0.f;
        #pragma unroll 8
        for (int tile = 0; tile < 128; tile++) s += pb[tile * 264 + c];
        tot[c] = 1.0f / s;
    }
    __syncthreads();
    hdg[b * 256 + c] = a * tot[c >> 5];
}

// K_vec2: 1 block x 256. ext_vec = hd@Wo^T+b; ext_gate = sigmoid([ml,ev]@Wge^T+b).
__global__ __launch_bounds__(256) void k_vec2(const unsigned short* __restrict__ WF,
                                              const float* __restrict__ hdg,
                                              const float* __restrict__ mean_low,
                                              const float* __restrict__ ext_out_b,
                                              const float* __restrict__ gate_ext_b,
                                              float* __restrict__ ext_vec,
                                              float* __restrict__ ext_gate) {
    __shared__ unsigned short xA[16][264];   // hd
    __shared__ unsigned short xB[16][264];   // mean_low
    __shared__ unsigned short xC[16][264];   // ev
    int t = threadIdx.x;
    int w = t >> 6, lane = t & 63, l15 = lane & 15, lhi = lane >> 4;
    const unsigned short* WoF    = WF + 278528;
    const unsigned short* WgeLoF = WF + 344064;
    const unsigned short* WgeHiF = WF + 409600;
    {
        int bb = t >> 5, kb = t & 31;
        #pragma unroll
        for (int q = 0; q < 4; q++) {
            int k0 = (kb + 32 * q) * 2;
            *(unsigned int*)&xA[bb][k0] =
                (unsigned int)f2b(hdg[bb * 256 + k0]) | ((unsigned int)f2b(hdg[bb * 256 + k0 + 1]) << 16);
            *(unsigned int*)&xB[bb][k0] =
                (unsigned int)f2b(mean_low[bb * 256 + k0]) | ((unsigned int)f2b(mean_low[bb * 256 + k0 + 1]) << 16);
        }
    }
    __syncthreads();
    // phase A: ext_vec
    {
        f32x4 acc[4] = {};
        for (int kk = 0; kk < 8; kk++) {
            bf16x8 a = *(const bf16x8*)&xA[l15][kk * 32 + 8 * lhi];
            #pragma unroll
            for (int ni = 0; ni < 4; ni++) {
                int ct = w * 4 + ni;
                bf16x8 bfr = *(const bf16x8*)(WoF + ((size_t)(ct * 8 + kk) << 9) + lane * 8);
                acc[ni] = __builtin_amdgcn_mfma_f32_16x16x32_bf16(a, bfr, acc[ni], 0, 0, 0);
            }
        }
        if (lhi < 2) {
            #pragma unroll
            for (int ni = 0; ni < 4; ni++) {
                int c = w * 64 + ni * 16 + l15;
                float bb = ext_out_b[c];
                #pragma unroll
                for (int r = 0; r < 4; r++) {
                    int b = 4 * lhi + r;
                    float val = acc[ni][r] + bb;
                    ext_vec[b * 256 + c] = val;
                    xC[b][c] = f2b(val);
                }
            }
        }
    }
    __syncthreads();
    // phase B: ext_gate
    {
        f32x4 acc[4] = {};
        for (int kk = 0; kk < 8; kk++) {
            bf16x8 a = *(const bf16x8*)&xB[l15][kk * 32 + 8 * lhi];
            #pragma unroll
            for (int ni = 0; ni < 4; ni++) {
                int ct = w * 4 + ni;
                bf16x8 bfr = *(const bf16x8*)(WgeLoF + ((size_t)(ct * 8 + kk) << 9) + lane * 8);
                acc[ni] = __builtin_amdgcn_mfma_f32_16x16x32_bf16(a, bfr, acc[ni], 0, 0, 0);
            }
        }
        for (int kk = 0; kk < 8; kk++) {
            bf16x8 a = *(const bf16x8*)&xC[l15][kk * 32 + 8 * lhi];
            #pragma unroll
            for (int ni = 0; ni < 4; ni++) {
                int ct = w * 4 + ni;
                bf16x8 bfr = *(const bf16x8*)(WgeHiF + ((size_t)(ct * 8 + kk) << 9) + lane * 8);
                acc[ni] = __builtin_amdgcn_mfma_f32_16x16x32_bf16(a, bfr, acc[ni], 0, 0, 0);
            }
        }
        if (lhi < 2) {
            #pragma unroll
            for (int ni = 0; ni < 4; ni++) {
                int c = w * 64 + ni * 16 + l15;
                float bb = gate_ext_b[c];
                #pragma unroll
                for (int r = 0; r < 4; r++) {
                    int b = 4 * lhi + r;
                    ext_gate[b * 256 + c] = 1.0f / (1.0f + expf(-(acc[ni][r] + bb)));
                }
            }
        }
    }
}

// ---------------------------------------------------------------------------
// K5: ext_final
__global__ __launch_bounds__(256) void k_ext_final(const float* __restrict__ low,
                                                   const float* __restrict__ ext_vec,
                                                   const float* __restrict__ ext_gate,
                                                   float* __restrict__ out) {
    int idx = blockIdx.x * 256 + threadIdx.x;
    #pragma unroll
    for (int rep = 0; rep < 4; ++rep) {
        int i = idx + rep * 524288;
        int bc = i >> 10;
        float g = ext_gate[bc];
        float vv = ext_vec[bc];
        f32x4 L = *(const f32x4*)(low + (size_t)i * 4);
        f32x4 o;
        #pragma unroll
        for (int c = 0; c < 4; c++) o[c] = L[c] + g * (vv - L[c]);
        *(f32x4*)(out + (size_t)i * 4) = o;
    }
}

// ---------------------------------------------------------------------------
// K6: road gate GEMM + elementwise. 32-px tiles, grid 1024, XCD-swizzled.
__global__ __launch_bounds__(512) void k_road(const float* __restrict__ high,
                                              const unsigned short* __restrict__ W3b,
                                              const float* __restrict__ rg_const,
                                              const float* __restrict__ road_vec,
                                              float* __restrict__ outbuf) {
    __shared__ float Xs[32 * 256];
    char* Xc = (char*)Xs;
    int bid = ((blockIdx.x & 7) << 7) | (blockIdx.x >> 3);   // XCD swizzle
    int b  = bid >> 7;
    int p0 = (bid & 127) << 5;
    int t  = threadIdx.x;
    const float* hb = high + (size_t)b * 1048576;

    int c0 = t >> 3;
    int j4 = (t & 7) * 4;
    #pragma unroll
    for (int it = 0; it < 4; ++it) {
        int c = c0 + 64 * it;
        f32x4 g = *(const f32x4*)(hb + (size_t)c * 4096 + p0 + j4);
        #pragma unroll
        for (int i = 0; i < 4; i++) {
            int j = j4 + i;
            *(float*)(Xc + ((j * 1024 + 4 * c) ^ ((j & 15) << 4))) = g[i];
        }
    }
    __syncthreads();

    int w = t >> 6, lane = t & 63, l15 = lane & 15, lhi = lane >> 4;
    f32x4 acc[2][2] = {};
    for (int kk = 0; kk < 8; kk++) {
        bf16x8 a[2];
        #pragma unroll
        for (int mi = 0; mi < 2; mi++) {
            int j = mi * 16 + l15;
            int base = j * 1024 + (kk * 32 + 8 * lhi) * 4;
            int sw = (j & 15) << 4;
            f32x4 x0 = *(const f32x4*)(Xc + (base ^ sw));
            f32x4 x1 = *(const f32x4*)(Xc + ((base + 16) ^ sw));
            bf16x8 av;
            #pragma unroll
            for (int i = 0; i < 4; i++) {
                av[i]     = (short)f2b(x0[i]);
                av[4 + i] = (short)f2b(x1[i]);
            }
            a[mi] = av;
        }
        #pragma unroll
        for (int ni = 0; ni < 2; ni++) {
            int o = w * 32 + ni * 16 + l15;
            bf16x8 bf = *(const bf16x8*)(W3b + (size_t)o * 256 + kk * 32 + 8 * lhi);
            acc[0][ni] = __builtin_amdgcn_mfma_f32_16x16x32_bf16(a[0], bf, acc[0][ni], 0, 0, 0);
            acc[1][ni] = __builtin_amdgcn_mfma_f32_16x16x32_bf16(a[1], bf, acc[1][ni], 0, 0, 0);
        }
    }
    __syncthreads();

    #pragma unroll
    for (int ni = 0; ni < 2; ni++) {
        int o = w * 32 + ni * 16 + l15;
        float rc = rg_const[b * 256 + o];
        float rv = road_vec[b * 256 + o];
        #pragma unroll
        for (int mi = 0; mi < 2; mi++)
            #pragma unroll
            for (int r = 0; r < 4; r++) {
                int j = mi * 16 + 4 * lhi + r;
                float* slot = (float*)(Xc + ((j * 1024 + 4 * o) ^ ((j & 15) << 4)));
                float z = acc[mi][ni][r] + rc;
                float gte = 1.0f / (1.0f + expf(-z));
                float hv = *slot;
                *slot = hv + gte * (rv - hv);
            }
    }
    __syncthreads();

    float* ob = outbuf + 8388608 + (size_t)b * 1048576;
    #pragma unroll
    for (int it = 0; it < 4; ++it) {
        int c = c0 + 64 * it;
        f32x4 o4;
        #pragma unroll
        for (int i = 0; i < 4; i++) {
            int j = j4 + i;
            o4[i] = *(const float*)(Xc + ((j * 1024 + 4 * c) ^ ((j & 15) << 4)));
        }
        *(f32x4*)(ob + (size_t)c * 4096 + p0 + j4) = o4;
    }
}

// ---------------------------------------------------------------------------
extern "C" void kernel_launch(void* const* d_in, const int* in_sizes, int n_in,
                              void* d_out, int out_size, void* d_ws, size_t ws_size,
                              hipStream_t stream) {
    const float* low         = (const float*)d_in[0];
    const float* high        = (const float*)d_in[1];
    const float* ext_context = (const float*)d_in[2];
    const float* road_feat   = (const float*)d_in[3];
    const float* ext_proj_w  = (const float*)d_in[4];
    const float* ext_proj_b  = (const float*)d_in[5];
    const float* road_proj_w = (const float*)d_in[6];
    const float* road_proj_b = (const float*)d_in[7];
    const float* ext_qkv_w   = (const float*)d_in[8];
    const float* ext_qkv_b   = (const float*)d_in[9];
    const float* road_qkv_w  = (const float*)d_in[10];
    const float* road_qkv_b  = (const float*)d_in[11];
    const float* ext_out_w   = (const float*)d_in[12];
    const float* ext_out_b   = (const float*)d_in[13];
    const float* road_out_w  = (const float*)d_in[14];
    const float* road_out_b  = (const float*)d_in[15];
    const float* gate_ext_w  = (const float*)d_in[16];
    const float* gate_ext_b  = (const float*)d_in[17];
    const float* gate_road_w = (const float*)d_in[18];
    const float* gate_road_b = (const float*)d_in[19];

    float* out = (float*)d_out;
    unsigned short* wsb = (unsigned short*)d_ws;
    unsigned short* Wcb = wsb;               // [0, 131072)
    unsigned short* W3b = wsb + 131072;      // [131072, 196608)
    float* fw = (float*)((char*)d_ws + 983040);
    float* ext_q    = fw;
    float* road_vec = fw + 2048;
    float* rg_const = fw + 4096;
    float* ext_vec  = fw + 8192;
    float* ext_gate = fw + 10240;
    float* mean_low = fw + 12288;
    float* bcv      = fw + 14336;
    float* hdg      = fw + 16384;            // 2048 floats
    float* part = out + 2097152;             // ext-half dead zone, pre-K5
    unsigned short* WF = (unsigned short*)(out + 4194304);  // 475136 ushorts, pre-K5

    k_setup<<<2496, 256, 0, stream>>>(road_proj_w, road_qkv_w, road_proj_b, road_qkv_b,
                                      gate_road_w, ext_proj_w, ext_qkv_w, road_out_w,
                                      ext_out_w, gate_ext_w, low,
                                      W3b, Wcb, WF, bcv, mean_low);
    k_tiny<<<1, 256, 0, stream>>>(WF, ext_context, ext_proj_b, ext_qkv_b,
                                  road_out_b, gate_road_b, ext_q, road_vec, rg_const);
    k_kv<<<1024, 512, 0, stream>>>(road_feat, Wcb, bcv, ext_q, part);
    k_vec_combine<<<8, 256, 0, stream>>>(part, hdg);
    k_vec2<<<1, 256, 0, stream>>>(WF, hdg, mean_low, ext_out_b, gate_ext_b,
                                  ext_vec, ext_gate);
    k_ext_final<<<2048, 256, 0, stream>>>(low, ext_vec, ext_gate, out);
    k_road<<<1024, 512, 0, stream>>>(high, W3b, rg_const, road_vec, out);
}

// Round 15
// 155.951 us; speedup vs baseline: 1.2105x; 1.0009x over previous
//
#include <hip/hip_runtime.h>

typedef short bf16x8 __attribute__((ext_vector_type(8)));
typedef float f32x4 __attribute__((ext_vector_type(4)));

__device__ __forceinline__ unsigned short f2b(float f) {
    unsigned int u = __builtin_bit_cast(unsigned int, f);
    unsigned int r = u + 0x7FFFu + ((u >> 16) & 1u);
    return (unsigned short)(r >> 16);
}
__device__ __forceinline__ float wsum64(float v) {
    #pragma unroll
    for (int m = 32; m; m >>= 1) v += __shfl_xor(v, m, 64);
    return v;
}

// WF fragment offsets (ushorts): Wq 0, Wv 65536, Wro 131072, Wg2 196608,
// Wp 262144, Wo 278528, WgeLo 344064, WgeHi 409600. total 475136.

// ---------------------------------------------------------------------------
// K_setup: all parallel prep. grid 2496 x 256.
__global__ __launch_bounds__(256) void k_setup(const float* __restrict__ w1,
                                               const float* __restrict__ wqkv,
                                               const float* __restrict__ b1,
                                               const float* __restrict__ bqkv,
                                               const float* __restrict__ gate_road_w,
                                               const float* __restrict__ ext_proj_w,
                                               const float* __restrict__ ext_qkv_w,
                                               const float* __restrict__ road_out_w,
                                               const float* __restrict__ ext_out_w,
                                               const float* __restrict__ gate_ext_w,
                                               const float* __restrict__ low,
                                               unsigned short* __restrict__ W3b,
                                               unsigned short* __restrict__ Wcb,
                                               unsigned short* __restrict__ WF,
                                               float* __restrict__ bcv,
                                               float* __restrict__ mean_low) {
    int bid = blockIdx.x, t = threadIdx.x;
    __shared__ float sel[8][256];
    __shared__ float red[8][4];
    if (bid >= 448) {
        int bc = bid - 448;
        const f32x4* p4 = (const f32x4*)(low + (size_t)bc * 4096);
        float s = 0.f;
        for (int i = t; i < 1024; i += 256) {
            f32x4 v = p4[i];
            s += v[0] + v[1] + v[2] + v[3];
        }
        s = wsum64(s);
        if ((t & 63) == 0) red[0][t >> 6] = s;
        __syncthreads();
        if (t == 0) mean_low[bc] = (red[0][0] + red[0][1] + red[0][2] + red[0][3]) * (1.0f / 4096.0f);
    } else if (bid < 256) {
        int i = bid * 256 + t;
        int o = i >> 8, k = i & 255;
        W3b[i] = f2b(gate_road_w[o * 512 + k]);
    } else if (bid < 320) {
        int o0 = (bid - 256) * 8;
        #pragma unroll
        for (int r = 0; r < 8; r++) {
            int o = o0 + r;
            int c = (o < 256) ? o : o - 256;
            int g = (o < 256) ? 1 : 2;
            sel[r][t] = wqkv[(size_t)(3 * c + g) * 256 + t];
        }
        __syncthreads();
        float b1v = b1[t];
        #pragma unroll
        for (int r = 0; r < 8; r++) {
            float v = wsum64(sel[r][t] * b1v);
            if ((t & 63) == 0) red[r][t >> 6] = v;
        }
        __syncthreads();
        if (t < 8) {
            int o = o0 + t;
            int c = (o < 256) ? o : o - 256;
            int g = (o < 256) ? 1 : 2;
            bcv[o] = red[t][0] + red[t][1] + red[t][2] + red[t][3] + bqkv[3 * c + g];
        }
        float acc[8] = {};
        #pragma unroll 16
        for (int m = 0; m < 256; m++) {
            float w1v = w1[(size_t)m * 256 + t];
            #pragma unroll
            for (int r = 0; r < 8; r++) acc[r] += sel[r][m] * w1v;
        }
        #pragma unroll
        for (int r = 0; r < 8; r++) Wcb[(size_t)(o0 + r) * 256 + t] = f2b(acc[r]);
    } else {
        int mb = bid - 320;
        int m = mb >> 4, ctile = mb & 15;
        const float* src;
        int stride, K, coff;
        unsigned short* dst;
        switch (m) {
        case 0: src = ext_qkv_w;                     stride = 256; K = 256; coff = 0;   dst = WF;          break;
        case 1: src = ext_qkv_w + (size_t)512 * 256; stride = 256; K = 256; coff = 0;   dst = WF + 65536;  break;
        case 2: src = road_out_w;                    stride = 256; K = 256; coff = 0;   dst = WF + 131072; break;
        case 3: src = gate_road_w;                   stride = 512; K = 256; coff = 256; dst = WF + 196608; break;
        case 4: src = ext_proj_w;                    stride = 64;  K = 64;  coff = 0;   dst = WF + 262144; break;
        case 5: src = ext_out_w;                     stride = 256; K = 256; coff = 0;   dst = WF + 278528; break;
        case 6: src = gate_ext_w;                    stride = 512; K = 256; coff = 0;   dst = WF + 344064; break;
        default: src = gate_ext_w;                   stride = 512; K = 256; coff = 256; dst = WF + 409600; break;
        }
        int lc = t >> 4, kseg = t & 15;
        int k0 = kseg * 16;
        if (k0 < K) {
            int c = ctile * 16 + lc;
            const float* sp = src + (size_t)c * stride + coff + k0;
            f32x4 v0 = *(const f32x4*)sp;
            f32x4 v1 = *(const f32x4*)(sp + 4);
            f32x4 v2 = *(const f32x4*)(sp + 8);
            f32x4 v3 = *(const f32x4*)(sp + 12);
            int kk = kseg >> 1;
            int Kt = K >> 5;
            #pragma unroll
            for (int h = 0; h < 2; h++) {
                int lhi = (kseg & 1) * 2 + h;
                int lane = lhi * 16 + lc;
                bf16x8 o;
                f32x4 a = h ? v2 : v0, b = h ? v3 : v1;
                #pragma unroll
                for (int i = 0; i < 4; i++) { o[i] = (short)f2b(a[i]); o[4 + i] = (short)f2b(b[i]); }
                *(bf16x8*)(dst + ((size_t)(ctile * Kt + kk) << 9) + lane * 8) = o;
            }
        }
    }
}

// ---------------------------------------------------------------------------
// K_tiny: 4-hop vector chain via MFMA, 1 block x 256.
__global__ __launch_bounds__(256) void k_tiny(const unsigned short* __restrict__ WF,
                                              const float* __restrict__ ext_context,
                                              const float* __restrict__ ext_proj_b,
                                              const float* __restrict__ ext_qkv_b,
                                              const float* __restrict__ road_out_b,
                                              const float* __restrict__ gate_road_b,
                                              float* __restrict__ ext_q,
                                              float* __restrict__ road_vec,
                                              float* __restrict__ rg_const) {
    __shared__ unsigned short xA[16][264];
    __shared__ unsigned short xB[16][264];
    int t = threadIdx.x;
    int w = t >> 6, lane = t & 63, l15 = lane & 15, lhi = lane >> 4;
    const unsigned short* WqF  = WF;
    const unsigned short* WvF  = WF + 65536;
    const unsigned short* WroF = WF + 131072;
    const unsigned short* WgF  = WF + 196608;
    const unsigned short* WpF  = WF + 262144;
    {
        int b = t >> 5, k0 = (t & 31) * 2;
        float c0v = ext_context[b * 64 + k0];
        float c1v = ext_context[b * 64 + k0 + 1];
        *(unsigned int*)&xA[b][k0] = (unsigned int)f2b(c0v) | ((unsigned int)f2b(c1v) << 16);
    }
    __syncthreads();
    {
        f32x4 acc[4] = {};
        #pragma unroll
        for (int kk = 0; kk < 2; kk++) {
            bf16x8 a = *(const bf16x8*)&xA[l15][kk * 32 + 8 * lhi];
            #pragma unroll
            for (int ni = 0; ni < 4; ni++) {
                int ct = w * 4 + ni;
                bf16x8 bfr = *(const bf16x8*)(WpF + ((size_t)(ct * 2 + kk) << 9) + lane * 8);
                acc[ni] = __builtin_amdgcn_mfma_f32_16x16x32_bf16(a, bfr, acc[ni], 0, 0, 0);
            }
        }
        if (lhi < 2) {
            #pragma unroll
            for (int ni = 0; ni < 4; ni++) {
                int c = w * 64 + ni * 16 + l15;
                float bp = ext_proj_b[c];
                #pragma unroll
                for (int r = 0; r < 4; r++)
                    xB[4 * lhi + r][c] = f2b(acc[ni][r] + bp);
            }
        }
    }
    __syncthreads();
    {
        f32x4 acc[8] = {};
        bool isq = (w < 2);
        int cbase = (w & 1) * 128;
        const unsigned short* Wb = isq ? WqF : WvF;
        for (int kk = 0; kk < 8; kk++) {
            bf16x8 a = *(const bf16x8*)&xB[l15][kk * 32 + 8 * lhi];
            #pragma unroll
            for (int ni = 0; ni < 8; ni++) {
                int ct = (cbase >> 4) + ni;
                bf16x8 bfr = *(const bf16x8*)(Wb + ((size_t)(ct * 8 + kk) << 9) + lane * 8);
                acc[ni] = __builtin_amdgcn_mfma_f32_16x16x32_bf16(a, bfr, acc[ni], 0, 0, 0);
            }
        }
        if (lhi < 2) {
            #pragma unroll
            for (int ni = 0; ni < 8; ni++) {
                int c = cbase + ni * 16 + l15;
                float bb = ext_qkv_b[(isq ? 0 : 512) + c];
                #pragma unroll
                for (int r = 0; r < 4; r++) {
                    int b = 4 * lhi + r;
                    float val = acc[ni][r] + bb;
                    if (isq) ext_q[b * 256 + c] = val;
                    else     xA[b][c] = f2b(val);
                }
            }
        }
    }
    __syncthreads();
    {
        f32x4 acc[4] = {};
        for (int kk = 0; kk < 8; kk++) {
            bf16x8 a = *(const bf16x8*)&xA[l15][kk * 32 + 8 * lhi];
            #pragma unroll
            for (int ni = 0; ni < 4; ni++) {
                int ct = w * 4 + ni;
                bf16x8 bfr = *(const bf16x8*)(WroF + ((size_t)(ct * 8 + kk) << 9) + lane * 8);
                acc[ni] = __builtin_amdgcn_mfma_f32_16x16x32_bf16(a, bfr, acc[ni], 0, 0, 0);
            }
        }
        if (lhi < 2) {
            #pragma unroll
            for (int ni = 0; ni < 4; ni++) {
                int c = w * 64 + ni * 16 + l15;
                float bb = road_out_b[c];
                #pragma unroll
                for (int r = 0; r < 4; r++) {
                    int b = 4 * lhi + r;
                    float val = acc[ni][r] + bb;
                    road_vec[b * 256 + c] = val;
                    xB[b][c] = f2b(val);
                }
            }
        }
    }
    __syncthreads();
    {
        f32x4 acc[4] = {};
        for (int kk = 0; kk < 8; kk++) {
            bf16x8 a = *(const bf16x8*)&xB[l15][kk * 32 + 8 * lhi];
            #pragma unroll
            for (int ni = 0; ni < 4; ni++) {
                int ct = w * 4 + ni;
                bf16x8 bfr = *(const bf16x8*)(WgF + ((size_t)(ct * 8 + kk) << 9) + lane * 8);
                acc[ni] = __builtin_amdgcn_mfma_f32_16x16x32_bf16(a, bfr, acc[ni], 0, 0, 0);
            }
        }
        if (lhi < 2) {
            #pragma unroll
            for (int ni = 0; ni < 4; ni++) {
                int c = w * 64 + ni * 16 + l15;
                float bb = gate_road_b[c];
                #pragma unroll
                for (int r = 0; r < 4; r++)
                    rg_const[(4 * lhi + r) * 256 + c] = acc[ni][r] + bb;
            }
        }
    }
}

// ---------------------------------------------------------------------------
// K_kv: head-per-wave fused KV-GEMM + attention partials. 32-px tiles,
// grid 1024 (no swizzle). Wave w owns head w: 32 K-rows + 32 V-rows.
// Single barrier (after staging); esh is intra-wave (DS in-order).
__global__ __launch_bounds__(512) void k_kv(const float* __restrict__ road_feat,
                                            const unsigned short* __restrict__ Wcb,
                                            const float* __restrict__ bcv,
                                            const float* __restrict__ extq,
                                            float* __restrict__ part) {
    __shared__ unsigned short Xs[32 * 256];
    __shared__ float esh[8][32];
    char* Xc = (char*)Xs;
    int bid = blockIdx.x;
    int b  = bid >> 7;
    int p0 = (bid & 127) << 5;
    int t  = threadIdx.x;
    const float* rfb = road_feat + (size_t)b * 1048576;

    int c0 = 2 * (t >> 3);
    int j4 = (t & 7) * 4;
    #pragma unroll
    for (int it = 0; it < 2; ++it) {
        int c = c0 + 128 * it;
        f32x4 g0 = *(const f32x4*)(rfb + (size_t)c * 4096 + p0 + j4);
        f32x4 g1 = *(const f32x4*)(rfb + (size_t)(c + 1) * 4096 + p0 + j4);
        #pragma unroll
        for (int i = 0; i < 4; i++) {
            int j = j4 + i;
            unsigned int pk = (unsigned int)f2b(g0[i]) | ((unsigned int)f2b(g1[i]) << 16);
            *(unsigned int*)(Xc + ((j * 512 + 2 * c) ^ ((j & 15) << 4))) = pk;
        }
    }
    __syncthreads();

    int w = t >> 6, lane = t & 63, l15 = lane & 15, lhi = lane >> 4;

    // GEMM: ni 0,1 -> K rows w*32+ni*16 ; ni 2,3 -> V rows 256+w*32+(ni-2)*16
    f32x4 acc[2][4] = {};
    for (int kk = 0; kk < 8; kk++) {
        bf16x8 a[2];
        #pragma unroll
        for (int mi = 0; mi < 2; mi++) {
            int j = mi * 16 + l15;
            int off = (j * 512 + (kk * 32 + 8 * lhi) * 2) ^ ((j & 15) << 4);
            a[mi] = *(const bf16x8*)((const char*)Xs + off);
        }
        #pragma unroll
        for (int ni = 0; ni < 4; ni++) {
            int n = (ni < 2) ? (w * 32 + ni * 16 + l15) : (256 + w * 32 + (ni - 2) * 16 + l15);
            bf16x8 bf = *(const bf16x8*)(Wcb + (size_t)n * 256 + kk * 32 + 8 * lhi);
            acc[0][ni] = __builtin_amdgcn_mfma_f32_16x16x32_bf16(a[0], bf, acc[0][ni], 0, 0, 0);
            acc[1][ni] = __builtin_amdgcn_mfma_f32_16x16x32_bf16(a[1], bf, acc[1][ni], 0, 0, 0);
        }
    }

    // scores for head w (all waves in parallel)
    float q0 = extq[b * 256 + w * 32 + l15];
    float q1 = extq[b * 256 + w * 32 + 16 + l15];
    float bk0 = bcv[w * 32 + l15];
    float bk1 = bcv[w * 32 + 16 + l15];
    #pragma unroll
    for (int mi = 0; mi < 2; mi++)
        #pragma unroll
        for (int r = 0; r < 4; r++) {
            int j = mi * 16 + 4 * lhi + r;
            float s = (acc[mi][0][r] + bk0) * q0 + (acc[mi][1][r] + bk1) * q1;
            s += __shfl_xor(s, 1, 64);
            s += __shfl_xor(s, 2, 64);
            s += __shfl_xor(s, 4, 64);
            s += __shfl_xor(s, 8, 64);
            if (l15 == 0)
                esh[w][j] = expf(s * 0.17677669529663687f);
        }

    float* pb = part + (size_t)bid * 264;
    // per-head sum of es (intra-wave: DS ops of this wave are in-order)
    {
        float v0 = esh[w][lane & 31];
        v0 += __shfl_xor(v0, 1, 64);
        v0 += __shfl_xor(v0, 2, 64);
        v0 += __shfl_xor(v0, 4, 64);
        v0 += __shfl_xor(v0, 8, 64);
        v0 += __shfl_xor(v0, 16, 64);
        if (lane == 0) pb[w] = v0;
    }
    // PV for head w's 32 V-channels
    #pragma unroll
    for (int vi = 0; vi < 2; vi++) {
        int cv = w * 32 + vi * 16 + l15;
        float bv = bcv[256 + cv];
        float p = 0.f;
        #pragma unroll
        for (int mi = 0; mi < 2; mi++)
            #pragma unroll
            for (int r = 0; r < 4; r++) {
                int j = mi * 16 + 4 * lhi + r;
                p += esh[w][j] * (acc[mi][2 + vi][r] + bv);
            }
        p += __shfl_xor(p, 16, 64);
        p += __shfl_xor(p, 32, 64);
        if (lhi == 0) pb[8 + cv] = p;
    }
}

// ---------------------------------------------------------------------------
// K_vec_combine: 8 blocks x 256. Coalesced reduction of attention partials.
__global__ __launch_bounds__(256) void k_vec_combine(const float* __restrict__ part,
                                                     float* __restrict__ hdg) {
    int b = blockIdx.x, c = threadIdx.x;
    __shared__ float tot[8];
    const float* pb = part + (size_t)b * 128 * 264;
    float a = 0.f;
    #pragma unroll 8
    for (int tile = 0; tile < 128; tile++) a += pb[tile * 264 + 8 + c];
    if (c < 8) {
        float s = 0.f;
        #pragma unroll 8
        for (int tile = 0; tile < 128; tile++) s += pb[tile * 264 + c];
        tot[c] = 1.0f / s;
    }
    __syncthreads();
    hdg[b * 256 + c] = a * tot[c >> 5];
}

// K_vec2: 1 block x 256. ext_vec = hd@Wo^T+b; ext_gate = sigmoid([ml,ev]@Wge^T+b).
__global__ __launch_bounds__(256) void k_vec2(const unsigned short* __restrict__ WF,
                                              const float* __restrict__ hdg,
                                              const float* __restrict__ mean_low,
                                              const float* __restrict__ ext_out_b,
                                              const float* __restrict__ gate_ext_b,
                                              float* __restrict__ ext_vec,
                                              float* __restrict__ ext_gate) {
    __shared__ unsigned short xA[16][264];
    __shared__ unsigned short xB[16][264];
    __shared__ unsigned short xC[16][264];
    int t = threadIdx.x;
    int w = t >> 6, lane = t & 63, l15 = lane & 15, lhi = lane >> 4;
    const unsigned short* WoF    = WF + 278528;
    const unsigned short* WgeLoF = WF + 344064;
    const unsigned short* WgeHiF = WF + 409600;
    {
        int bb = t >> 5, kb = t & 31;
        #pragma unroll
        for (int q = 0; q < 4; q++) {
            int k0 = (kb + 32 * q) * 2;
            *(unsigned int*)&xA[bb][k0] =
                (unsigned int)f2b(hdg[bb * 256 + k0]) | ((unsigned int)f2b(hdg[bb * 256 + k0 + 1]) << 16);
            *(unsigned int*)&xB[bb][k0] =
                (unsigned int)f2b(mean_low[bb * 256 + k0]) | ((unsigned int)f2b(mean_low[bb * 256 + k0 + 1]) << 16);
        }
    }
    __syncthreads();
    {
        f32x4 acc[4] = {};
        for (int kk = 0; kk < 8; kk++) {
            bf16x8 a = *(const bf16x8*)&xA[l15][kk * 32 + 8 * lhi];
            #pragma unroll
            for (int ni = 0; ni < 4; ni++) {
                int ct = w * 4 + ni;
                bf16x8 bfr = *(const bf16x8*)(WoF + ((size_t)(ct * 8 + kk) << 9) + lane * 8);
                acc[ni] = __builtin_amdgcn_mfma_f32_16x16x32_bf16(a, bfr, acc[ni], 0, 0, 0);
            }
        }
        if (lhi < 2) {
            #pragma unroll
            for (int ni = 0; ni < 4; ni++) {
                int c = w * 64 + ni * 16 + l15;
                float bb = ext_out_b[c];
                #pragma unroll
                for (int r = 0; r < 4; r++) {
                    int b = 4 * lhi + r;
                    float val = acc[ni][r] + bb;
                    ext_vec[b * 256 + c] = val;
                    xC[b][c] = f2b(val);
                }
            }
        }
    }
    __syncthreads();
    {
        f32x4 acc[4] = {};
        for (int kk = 0; kk < 8; kk++) {
            bf16x8 a = *(const bf16x8*)&xB[l15][kk * 32 + 8 * lhi];
            #pragma unroll
            for (int ni = 0; ni < 4; ni++) {
                int ct = w * 4 + ni;
                bf16x8 bfr = *(const bf16x8*)(WgeLoF + ((size_t)(ct * 8 + kk) << 9) + lane * 8);
                acc[ni] = __builtin_amdgcn_mfma_f32_16x16x32_bf16(a, bfr, acc[ni], 0, 0, 0);
            }
        }
        for (int kk = 0; kk < 8; kk++) {
            bf16x8 a = *(const bf16x8*)&xC[l15][kk * 32 + 8 * lhi];
            #pragma unroll
            for (int ni = 0; ni < 4; ni++) {
                int ct = w * 4 + ni;
                bf16x8 bfr = *(const bf16x8*)(WgeHiF + ((size_t)(ct * 8 + kk) << 9) + lane * 8);
                acc[ni] = __builtin_amdgcn_mfma_f32_16x16x32_bf16(a, bfr, acc[ni], 0, 0, 0);
            }
        }
        if (lhi < 2) {
            #pragma unroll
            for (int ni = 0; ni < 4; ni++) {
                int c = w * 64 + ni * 16 + l15;
                float bb = gate_ext_b[c];
                #pragma unroll
                for (int r = 0; r < 4; r++) {
                    int b = 4 * lhi + r;
                    ext_gate[b * 256 + c] = 1.0f / (1.0f + expf(-(acc[ni][r] + bb)));
                }
            }
        }
    }
}

// ---------------------------------------------------------------------------
// K5: ext_final
__global__ __launch_bounds__(256) void k_ext_final(const float* __restrict__ low,
                                                   const float* __restrict__ ext_vec,
                                                   const float* __restrict__ ext_gate,
                                                   float* __restrict__ out) {
    int idx = blockIdx.x * 256 + threadIdx.x;
    #pragma unroll
    for (int rep = 0; rep < 4; ++rep) {
        int i = idx + rep * 524288;
        int bc = i >> 10;
        float g = ext_gate[bc];
        float vv = ext_vec[bc];
        f32x4 L = *(const f32x4*)(low + (size_t)i * 4);
        f32x4 o;
        #pragma unroll
        for (int c = 0; c < 4; c++) o[c] = L[c] + g * (vv - L[c]);
        *(f32x4*)(out + (size_t)i * 4) = o;
    }
}

// ---------------------------------------------------------------------------
// K6: road gate GEMM + elementwise. 32-px tiles, grid 1024 (no swizzle).
__global__ __launch_bounds__(512) void k_road(const float* __restrict__ high,
                                              const unsigned short* __restrict__ W3b,
                                              const float* __restrict__ rg_const,
                                              const float* __restrict__ road_vec,
                                              float* __restrict__ outbuf) {
    __shared__ float Xs[32 * 256];
    char* Xc = (char*)Xs;
    int bid = blockIdx.x;
    int b  = bid >> 7;
    int p0 = (bid & 127) << 5;
    int t  = threadIdx.x;
    const float* hb = high + (size_t)b * 1048576;

    int c0 = t >> 3;
    int j4 = (t & 7) * 4;
    #pragma unroll
    for (int it = 0; it < 4; ++it) {
        int c = c0 + 64 * it;
        f32x4 g = *(const f32x4*)(hb + (size_t)c * 4096 + p0 + j4);
        #pragma unroll
        for (int i = 0; i < 4; i++) {
            int j = j4 + i;
            *(float*)(Xc + ((j * 1024 + 4 * c) ^ ((j & 15) << 4))) = g[i];
        }
    }
    __syncthreads();

    int w = t >> 6, lane = t & 63, l15 = lane & 15, lhi = lane >> 4;
    f32x4 acc[2][2] = {};
    for (int kk = 0; kk < 8; kk++) {
        bf16x8 a[2];
        #pragma unroll
        for (int mi = 0; mi < 2; mi++) {
            int j = mi * 16 + l15;
            int base = j * 1024 + (kk * 32 + 8 * lhi) * 4;
            int sw = (j & 15) << 4;
            f32x4 x0 = *(const f32x4*)(Xc + (base ^ sw));
            f32x4 x1 = *(const f32x4*)(Xc + ((base + 16) ^ sw));
            bf16x8 av;
            #pragma unroll
            for (int i = 0; i < 4; i++) {
                av[i]     = (short)f2b(x0[i]);
                av[4 + i] = (short)f2b(x1[i]);
            }
            a[mi] = av;
        }
        #pragma unroll
        for (int ni = 0; ni < 2; ni++) {
            int o = w * 32 + ni * 16 + l15;
            bf16x8 bf = *(const bf16x8*)(W3b + (size_t)o * 256 + kk * 32 + 8 * lhi);
            acc[0][ni] = __builtin_amdgcn_mfma_f32_16x16x32_bf16(a[0], bf, acc[0][ni], 0, 0, 0);
            acc[1][ni] = __builtin_amdgcn_mfma_f32_16x16x32_bf16(a[1], bf, acc[1][ni], 0, 0, 0);
        }
    }
    __syncthreads();

    #pragma unroll
    for (int ni = 0; ni < 2; ni++) {
        int o = w * 32 + ni * 16 + l15;
        float rc = rg_const[b * 256 + o];
        float rv = road_vec[b * 256 + o];
        #pragma unroll
        for (int mi = 0; mi < 2; mi++)
            #pragma unroll
            for (int r = 0; r < 4; r++) {
                int j = mi * 16 + 4 * lhi + r;
                float* slot = (float*)(Xc + ((j * 1024 + 4 * o) ^ ((j & 15) << 4)));
                float z = acc[mi][ni][r] + rc;
                float gte = 1.0f / (1.0f + expf(-z));
                float hv = *slot;
                *slot = hv + gte * (rv - hv);
            }
    }
    __syncthreads();

    float* ob = outbuf + 8388608 + (size_t)b * 1048576;
    #pragma unroll
    for (int it = 0; it < 4; ++it) {
        int c = c0 + 64 * it;
        f32x4 o4;
        #pragma unroll
        for (int i = 0; i < 4; i++) {
            int j = j4 + i;
            o4[i] = *(const float*)(Xc + ((j * 1024 + 4 * c) ^ ((j & 15) << 4)));
        }
        *(f32x4*)(ob + (size_t)c * 4096 + p0 + j4) = o4;
    }
}

// ---------------------------------------------------------------------------
extern "C" void kernel_launch(void* const* d_in, const int* in_sizes, int n_in,
                              void* d_out, int out_size, void* d_ws, size_t ws_size,
                              hipStream_t stream) {
    const float* low         = (const float*)d_in[0];
    const float* high        = (const float*)d_in[1];
    const float* ext_context = (const float*)d_in[2];
    const float* road_feat   = (const float*)d_in[3];
    const float* ext_proj_w  = (const float*)d_in[4];
    const float* ext_proj_b  = (const float*)d_in[5];
    const float* road_proj_w = (const float*)d_in[6];
    const float* road_proj_b = (const float*)d_in[7];
    const float* ext_qkv_w   = (const float*)d_in[8];
    const float* ext_qkv_b   = (const float*)d_in[9];
    const float* road_qkv_w  = (const float*)d_in[10];
    const float* road_qkv_b  = (const float*)d_in[11];
    const float* ext_out_w   = (const float*)d_in[12];
    const float* ext_out_b   = (const float*)d_in[13];
    const float* road_out_w  = (const float*)d_in[14];
    const float* road_out_b  = (const float*)d_in[15];
    const float* gate_ext_w  = (const float*)d_in[16];
    const float* gate_ext_b  = (const float*)d_in[17];
    const float* gate_road_w = (const float*)d_in[18];
    const float* gate_road_b = (const float*)d_in[19];

    float* out = (float*)d_out;
    unsigned short* wsb = (unsigned short*)d_ws;
    unsigned short* Wcb = wsb;               // [0, 131072)
    unsigned short* W3b = wsb + 131072;      // [131072, 196608)
    float* fw = (float*)((char*)d_ws + 983040);
    float* ext_q    = fw;
    float* road_vec = fw + 2048;
    float* rg_const = fw + 4096;
    float* ext_vec  = fw + 8192;
    float* ext_gate = fw + 10240;
    float* mean_low = fw + 12288;
    float* bcv      = fw + 14336;
    float* hdg      = fw + 16384;
    float* part = out + 2097152;             // ext-half dead zone, pre-K5
    unsigned short* WF = (unsigned short*)(out + 4194304);  // pre-K5 dead zone

    k_setup<<<2496, 256, 0, stream>>>(road_proj_w, road_qkv_w, road_proj_b, road_qkv_b,
                                      gate_road_w, ext_proj_w, ext_qkv_w, road_out_w,
                                      ext_out_w, gate_ext_w, low,
                                      W3b, Wcb, WF, bcv, mean_low);
    k_tiny<<<1, 256, 0, stream>>>(WF, ext_context, ext_proj_b, ext_qkv_b,
                                  road_out_b, gate_road_b, ext_q, road_vec, rg_const);
    k_kv<<<1024, 512, 0, stream>>>(road_feat, Wcb, bcv, ext_q, part);
    k_vec_combine<<<8, 256, 0, stream>>>(part, hdg);
    k_vec2<<<1, 256, 0, stream>>>(WF, hdg, mean_low, ext_out_b, gate_ext_b,
                                  ext_vec, ext_gate);
    k_ext_final<<<2048, 256, 0, stream>>>(low, ext_vec, ext_gate, out);
    k_road<<<1024, 512, 0, stream>>>(high, W3b, rg_const, road_vec, out);
}